// Round 1
// baseline (257.475 us; speedup 1.0000x reference)
//
#include <hip/hip_runtime.h>
#include <hip/hip_bf16.h>
#include <hip/hip_cooperative_groups.h>
#include <math.h>

#define NB 64
#define CC 512
#define LL 256

namespace cg = cooperative_groups;

typedef __attribute__((ext_vector_type(4))) float floatx4;
typedef __attribute__((ext_vector_type(8))) short short8;

static __device__ __forceinline__ unsigned f2bf2(float x, float y) {
    __hip_bfloat162 h = __float22bfloat162_rn(make_float2(x, y));
    union { __hip_bfloat162 h; unsigned u; } c; c.h = h;
    return c.u;   // low 16 = x, high 16 = y
}

// decode linear t -> upper-tri (tI,tJ) of a u x u tile grid
static __device__ __forceinline__ bool decode_tile(int t, int u, int& tI, int& tJ) {
    if (t >= (u * (u + 1)) >> 1) return false;
    tI = 0;
    while (t >= u - tI) { t -= u - tI; ++tI; }
    tJ = tI + t;
    return true;
}

struct __align__(16) SharedBlk {
    unsigned short lds[2][2][64][40];  // [A/B][dbuf][row][40 halves] = 20 KB
    float s_norm[2][2][64];            // [mat][A/B][row]
    float red[2][4];
};

// ---- one matrix's 64x64 Gram tile: stage bf16 + MFMA + inline norms ----
static __device__ __forceinline__ void gram64(
    const float* __restrict__ P, const int* __restrict__ idxn,
    int np, int tI, int tJ, bool diag, int tid,
    SharedBlk& sh, int mat, floatx4 (&acc)[4])
{
    const int w = tid >> 6, lane = tid & 63;
    const int srow = w * 32 + (lane >> 1);
    const int half = lane & 1;
    const bool stager = diag ? (srow < 64) : true;
    const int ab = srow >> 6, rloc = srow & 63;
    const int gk = (ab ? tJ : tI) * 64 + rloc;
    const int row = idxn[(gk < np) ? gk : 0];
    const char* rp = (const char*)P + (size_t)row * (LL * 4) + half * 64;

    float4 pre[4];
    float nsum = 0.0f;
    if (stager) {
        #pragma unroll
        for (int i = 0; i < 4; ++i) pre[i] = *(const float4*)(rp + i * 16);
    }
    const int m16 = lane & 15, quad = lane >> 4;
    const int bufB = diag ? 0 : 1;
    const int wrow = w * 16;

    for (int kk = 0; kk < 8; ++kk) {
        const int pb = kk & 1;
        if (stager) {
            #pragma unroll
            for (int i = 0; i < 4; ++i)
                nsum += pre[i].x * pre[i].x + pre[i].y * pre[i].y +
                        pre[i].z * pre[i].z + pre[i].w * pre[i].w;
            unsigned short* dst = &sh.lds[ab][pb][rloc][half * 16];
            *(uint2*)(dst + 0)  = make_uint2(f2bf2(pre[0].x, pre[0].y), f2bf2(pre[0].z, pre[0].w));
            *(uint2*)(dst + 4)  = make_uint2(f2bf2(pre[1].x, pre[1].y), f2bf2(pre[1].z, pre[1].w));
            *(uint2*)(dst + 8)  = make_uint2(f2bf2(pre[2].x, pre[2].y), f2bf2(pre[2].z, pre[2].w));
            *(uint2*)(dst + 12) = make_uint2(f2bf2(pre[3].x, pre[3].y), f2bf2(pre[3].z, pre[3].w));
        }
        __syncthreads();   // single barrier per chunk
        if (stager && kk < 7) {
            #pragma unroll
            for (int i = 0; i < 4; ++i)
                pre[i] = *(const float4*)(rp + (kk + 1) * 128 + i * 16);
        }
        const short8 a = *(const short8*)&sh.lds[0][pb][wrow + m16][quad * 8];
        #pragma unroll
        for (int c = 0; c < 4; ++c) {
            const short8 b = *(const short8*)&sh.lds[bufB][pb][c * 16 + m16][quad * 8];
            acc[c] = __builtin_amdgcn_mfma_f32_16x16x32_bf16(a, b, acc[c], 0, 0, 0);
        }
    }
    if (stager) {   // 2 lanes share each staged row
        const float v = nsum + __shfl_xor(nsum, 1);
        if (half == 0) sh.s_norm[mat][ab][rloc] = v;
    }
}

// ---- distances from Gram acc; C/D layout: col=lane&15, row=quad*4+reg ----
static __device__ __forceinline__ float dists64(
    const floatx4 (&acc)[4], SharedBlk& sh, int mat, int bufB,
    int np, int tI, int tJ, int tid, float (&d)[4][4])
{
    const int lane = tid & 63;
    const int m16 = lane & 15, quad = lane >> 4;
    const int wrow = (tid >> 6) * 16;
    float l0 = 0.0f;
    #pragma unroll
    for (int c = 0; c < 4; ++c) {
        const int colL = c * 16 + m16;
        const int gj = tJ * 64 + colL;
        const float nB = sh.s_norm[mat][bufB][colL];
        #pragma unroll
        for (int r = 0; r < 4; ++r) {
            const int rowL = wrow + quad * 4 + r;
            const int gi = tI * 64 + rowL;
            const float dd = sqrtf(fmaxf(sh.s_norm[mat][0][rowL] + nB - 2.0f * acc[c][r], 1e-12f));
            d[c][r] = dd;
            if (gi < np && gj < np && gi != gj) l0 += dd;
        }
    }
    return l0;
}

// ---- full tile: S-gram + T-gram (shared staging addressing), dist sums ----
static __device__ __forceinline__ void do_tile(
    const float* __restrict__ Sb, const float* __restrict__ Tb,
    const int* __restrict__ idxn,
    int n, int np, int tI, int tJ, int tid,
    SharedBlk& sh, float* __restrict__ sumS, float* __restrict__ sumT,
    float (&dS)[4][4], float (&dT)[4][4])
{
    const bool diag = (tI == tJ);
    const int bufB = diag ? 0 : 1;

    floatx4 acc[4];
    #pragma unroll
    for (int c = 0; c < 4; ++c) { acc[c][0] = 0; acc[c][1] = 0; acc[c][2] = 0; acc[c][3] = 0; }
    gram64(Sb, idxn, np, tI, tJ, diag, tid, sh, 0, acc);
    __syncthreads();   // norms visible
    const float l0S = dists64(acc, sh, 0, bufB, np, tI, tJ, tid, dS);

    #pragma unroll
    for (int c = 0; c < 4; ++c) { acc[c][0] = 0; acc[c][1] = 0; acc[c][2] = 0; acc[c][3] = 0; }
    gram64(Tb, idxn, np, tI, tJ, diag, tid, sh, 1, acc);
    __syncthreads();
    const float l0T = dists64(acc, sh, 1, bufB, np, tI, tJ, tid, dT);

    float a = l0S, b = l0T;
    #pragma unroll
    for (int o = 32; o; o >>= 1) { a += __shfl_down(a, o); b += __shfl_down(b, o); }
    const int w = tid >> 6, lane = tid & 63;
    if (lane == 0) { sh.red[0][w] = a; sh.red[1][w] = b; }
    __syncthreads();
    if (tid == 0) {
        const float wgt = diag ? 1.0f : 2.0f;   // off-diag tiles mirror-counted
        atomicAdd(sumS + n, wgt * (sh.red[0][0] + sh.red[0][1] + sh.red[0][2] + sh.red[0][3]));
        atomicAdd(sumT + n, wgt * (sh.red[1][0] + sh.red[1][1] + sh.red[1][2] + sh.red[1][3]));
    }
    __syncthreads();   // red[] safe for reuse
}

// ---- Huber contribution of one tile from register-resident distances ----
static __device__ __forceinline__ void huber_acc(
    const float (&dS)[4][4], const float (&dT)[4][4],
    float inv_ms, float inv_mt, int np, int tI, int tJ, int tid,
    SharedBlk& sh, float* __restrict__ out)
{
    const int lane = tid & 63;
    const int m16 = lane & 15, quad = lane >> 4;
    const int wrow = (tid >> 6) * 16;
    float h = 0.0f;
    #pragma unroll
    for (int c = 0; c < 4; ++c) {
        const int gj = tJ * 64 + c * 16 + m16;
        #pragma unroll
        for (int r = 0; r < 4; ++r) {
            const int gi = tI * 64 + wrow + quad * 4 + r;
            if (gi < np && gj < np && gi != gj) {
                const float diff = dS[c][r] * inv_ms - dT[c][r] * inv_mt;
                const float ad = fabsf(diff);
                h += (ad < 1.0f) ? 0.5f * diff * diff : ad - 0.5f;
            }
        }
    }
    #pragma unroll
    for (int o = 32; o; o >>= 1) h += __shfl_down(h, o);
    const int w = tid >> 6;
    if (lane == 0) sh.red[0][w] = h;
    __syncthreads();
    if (tid == 0) {
        const float wgt = (tI == tJ) ? 1.0f : 2.0f;
        atomicAdd(out, wgt * (sh.red[0][0] + sh.red[0][1] + sh.red[0][2] + sh.red[0][3]) / (float)np);
    }
    __syncthreads();   // red[] safe for reuse (extras loop)
}

// ================= fused cooperative kernel =================
// bid = t*64 + n  =>  bid % 8 == n % 8 (XCD-clustered per batch, L2 reuse of rows).
// Phase 0: prep (blocks 0..63). Phase A: S+T dist tile, sums, d kept in VGPRs.
// Phase B (after grid.sync): Huber from registers. t >= TSLOTS falls back to a
// global f32 spill path (never taken for np <= 320; correctness only).
__global__ __launch_bounds__(256, 4) void fused_kernel(
    const float* __restrict__ S, const float* __restrict__ T,
    const int* __restrict__ targets,
    int* __restrict__ idx, int* __restrict__ npos,
    float* __restrict__ sumS, float* __restrict__ sumT,
    float* __restrict__ DsF, float* __restrict__ DtF,
    float* __restrict__ out)
{
    __shared__ SharedBlk sh;
    const int bid = blockIdx.x, tid = threadIdx.x;
    cg::grid_group grid = cg::this_grid();

    // ---------- phase 0: per-batch ballot compaction ----------
    if (bid < NB) {
        const int n = bid;
        __shared__ int s_cnt[8], s_off[8];
        const int w = tid >> 6, lane = tid & 63;
        const int* tg = targets + n * CC;
        const bool p0 = tg[tid] != 0;
        const bool p1 = tg[tid + 256] != 0;
        const unsigned long long m0 = __ballot(p0);
        const unsigned long long m1 = __ballot(p1);
        if (lane == 0) { s_cnt[w] = __popcll(m0); s_cnt[4 + w] = __popcll(m1); }
        __syncthreads();
        if (tid == 0) {
            int a = 0;
            for (int i = 0; i < 8; ++i) { s_off[i] = a; a += s_cnt[i]; }
            npos[n] = a;
            sumS[n] = 0.0f; sumT[n] = 0.0f;
            if (n == 0) out[0] = 0.0f;
        }
        __syncthreads();
        const unsigned long long below = (1ull << lane) - 1ull;
        if (p0) idx[n * CC + s_off[w] + __popcll(m0 & below)] = tid;
        if (p1) idx[n * CC + s_off[4 + w] + __popcll(m1 & below)] = tid + 256;
    }
    grid.sync();

    // ---------- phase A: distance tiles + sums ----------
    const int n = bid & (NB - 1);
    const int TSLOTS = (int)(gridDim.x >> 6);
    const int tprim = bid >> 6;
    const int np = __hip_atomic_load(&npos[n], __ATOMIC_RELAXED, __HIP_MEMORY_SCOPE_AGENT);
    const int u = (np + 63) >> 6;
    const int ntiles = (np >= 2) ? ((u * (u + 1)) >> 1) : 0;
    const float* Sb = S + (size_t)n * CC * LL;
    const float* Tb = T + (size_t)n * CC * LL;
    const int* idxn = idx + n * CC;

    float dS[4][4], dT[4][4];
    int tI = 0, tJ = 0;
    const bool active = (tprim < ntiles);
    if (active) {
        decode_tile(tprim, u, tI, tJ);
        do_tile(Sb, Tb, idxn, n, np, tI, tJ, tid, sh, sumS, sumT, dS, dT);
    }
    // correctness fallback for tiles beyond the resident grid (np > 320)
    for (int t2 = tprim + TSLOTS; t2 < 36; t2 += TSLOTS) {
        if (t2 < ntiles) {
            int eI, eJ; decode_tile(t2, u, eI, eJ);
            float eS[4][4], eT[4][4];
            do_tile(Sb, Tb, idxn, n, np, eI, eJ, tid, sh, sumS, sumT, eS, eT);
            const size_t slot = ((size_t)t2 * NB + n) << 12;
            const int lane = tid & 63, m16 = lane & 15, quad = lane >> 4, wrow = (tid >> 6) * 16;
            #pragma unroll
            for (int c = 0; c < 4; ++c) {
                #pragma unroll
                for (int r = 0; r < 4; ++r) {
                    const int e = (wrow + quad * 4 + r) * 64 + c * 16 + m16;
                    DsF[slot + e] = eS[c][r];
                    DtF[slot + e] = eT[c][r];
                }
            }
        }
    }
    grid.sync();

    // ---------- phase B: Huber from registers ----------
    if (ntiles > 0) {
        const float cnt = (float)np * (float)(np - 1);
        const float ss = __hip_atomic_load(&sumS[n], __ATOMIC_RELAXED, __HIP_MEMORY_SCOPE_AGENT);
        const float st = __hip_atomic_load(&sumT[n], __ATOMIC_RELAXED, __HIP_MEMORY_SCOPE_AGENT);
        const float inv_ms = cnt / ss;
        const float inv_mt = cnt / st;
        if (active)
            huber_acc(dS, dT, inv_ms, inv_mt, np, tI, tJ, tid, sh, out);
        for (int t2 = tprim + TSLOTS; t2 < 36; t2 += TSLOTS) {
            if (t2 < ntiles) {
                int eI, eJ; decode_tile(t2, u, eI, eJ);
                float eS[4][4], eT[4][4];
                const size_t slot = ((size_t)t2 * NB + n) << 12;
                const int lane = tid & 63, m16 = lane & 15, quad = lane >> 4, wrow = (tid >> 6) * 16;
                #pragma unroll
                for (int c = 0; c < 4; ++c) {
                    #pragma unroll
                    for (int r = 0; r < 4; ++r) {
                        const int e = (wrow + quad * 4 + r) * 64 + c * 16 + m16;
                        eS[c][r] = DsF[slot + e];
                        eT[c][r] = DtF[slot + e];
                    }
                }
                huber_acc(eS, eT, inv_ms, inv_mt, np, eI, eJ, tid, sh, out);
            }
        }
    }
}

extern "C" void kernel_launch(void* const* d_in, const int* in_sizes, int n_in,
                              void* d_out, int out_size, void* d_ws, size_t ws_size,
                              hipStream_t stream) {
    const float* S = (const float*)d_in[0];
    const float* T = (const float*)d_in[1];
    const int* targets = (const int*)d_in[2];
    float* out = (float*)d_out;

    char* p = (char*)d_ws;
    int* idx = (int*)p;        p += (size_t)NB * CC * 4;
    int* npos = (int*)p;       p += NB * 4;
    float* sumS = (float*)p;   p += NB * 4;
    float* sumT = (float*)p;   p += NB * 4;
    p = (char*)(((size_t)p + 255) & ~(size_t)255);
    float* DsF = (float*)p;    p += (size_t)36 * NB * 4096 * 4;  // 37.7 MB fallback spill
    float* DtF = (float*)p;                                       // 37.7 MB fallback spill

    // co-residency: launch_bounds(256,4) caps VGPR at 128, LDS ~21.6 KB -> >=4 blocks/CU.
    static int maxblk = 0;
    if (maxblk == 0) {
        if (hipOccupancyMaxActiveBlocksPerMultiprocessor(&maxblk, fused_kernel, 256, 0) != hipSuccess
            || maxblk < 1) maxblk = 1;
    }
    int G = maxblk * 256;           // 256 CUs on MI355X
    if (G > 1024) G = 1024;         // 16 t-slots x 64 batches covers np <= 320
    G &= ~63;
    if (G < 64) G = 64;

    void* args[] = { (void*)&S, (void*)&T, (void*)&targets, (void*)&idx, (void*)&npos,
                     (void*)&sumS, (void*)&sumT, (void*)&DsF, (void*)&DtF, (void*)&out };
    hipLaunchCooperativeKernel((void*)fused_kernel, dim3(G), dim3(256), args, 0, stream);
}

// Round 2
// 122.207 us; speedup vs baseline: 2.1069x; 2.1069x over previous
//
#include <hip/hip_runtime.h>
#include <hip/hip_bf16.h>
#include <hip/hip_fp16.h>
#include <math.h>

#define NB 64
#define CC 512
#define LL 256

typedef __attribute__((ext_vector_type(4))) float floatx4;
typedef __attribute__((ext_vector_type(8))) short short8;

static __device__ __forceinline__ unsigned f2bf2(float x, float y) {
    __hip_bfloat162 h = __float22bfloat162_rn(make_float2(x, y));
    union { __hip_bfloat162 h; unsigned u; } c; c.h = h;
    return c.u;   // low 16 = x, high 16 = y
}
static __device__ __forceinline__ unsigned short f2h(float x) {
    __half h = __float2half_rn(x);
    union { __half h; unsigned short u; } c; c.h = h;
    return c.u;
}
static __device__ __forceinline__ float h2f(unsigned u) {
    union { unsigned short u; __half h; } c; c.u = (unsigned short)u;
    return __half2float(c.h);
}

// decode linear t -> upper-tri (tI,tJ) of a u x u tile grid
static __device__ __forceinline__ bool decode_tile(int t, int u, int& tI, int& tJ) {
    if (t >= (u * (u + 1)) >> 1) return false;
    tI = 0;
    while (t >= u - tI) { t -= u - tI; ++tI; }
    tJ = tI + t;
    return true;
}

// ---------------- K1: compaction-in-block + MFMA Gram + distances ----------------
// bx = (t*2+mat)*64 + n  =>  bx % 8 == n % 8 (XCD-clustered per batch).
// Each block: ballot-compacts its batch's targets into LDS (replaces the prep
// kernel + idx round-trip), then computes ONE matrix's (S or T) 64x64 distance
// tile exactly as the proven baseline. Tile distance sum -> UNIQUE slot
// sum[t][n] (plain store, weight folded) -- no atomics, no zero-init kernel.
__global__ __launch_bounds__(256) void dist_kernel(
    const float* __restrict__ S, const float* __restrict__ T,
    const int* __restrict__ targets,
    float* __restrict__ sumS, float* __restrict__ sumT,
    unsigned short* __restrict__ Ds, unsigned short* __restrict__ Dt,
    float* __restrict__ out)
{
    const int bx = blockIdx.x;
    const int n = bx & (NB - 1);
    const int q = bx >> 6;
    const int mat = q & 1, t = q >> 1;
    const int tid = threadIdx.x;
    const int w = tid >> 6, lane = tid & 63;

    // bf16 tiles [A/B][dbuf][row][40 halves] = 20 KB (+ idx 2 KB)
    __shared__ __align__(16) unsigned short lds[2][2][64][40];
    __shared__ float s_norm[2][64];
    __shared__ float red[4];
    __shared__ int s_idx[CC];
    __shared__ int s_cnt[8], s_off[8];
    __shared__ int s_np;

    if (bx == 0 && tid == 0) out[0] = 0.0f;   // huber runs strictly after (stream order)

    // ---- in-block ballot compaction (was prep_kernel) ----
    const int* tg = targets + n * CC;
    const bool p0 = tg[tid] != 0;
    const bool p1 = tg[tid + 256] != 0;
    const unsigned long long m0 = __ballot(p0);
    const unsigned long long m1 = __ballot(p1);
    if (lane == 0) { s_cnt[w] = __popcll(m0); s_cnt[4 + w] = __popcll(m1); }
    __syncthreads();
    if (tid == 0) {
        int a = 0;
        for (int i = 0; i < 8; ++i) { s_off[i] = a; a += s_cnt[i]; }
        s_np = a;
    }
    __syncthreads();
    const unsigned long long below = (1ull << lane) - 1ull;
    if (p0) s_idx[s_off[w] + __popcll(m0 & below)] = tid;
    if (p1) s_idx[s_off[4 + w] + __popcll(m1 & below)] = tid + 256;
    const int np = s_np;
    __syncthreads();   // s_idx visible

    if (np < 2) return;
    int tI, tJ;
    if (!decode_tile(t, (np + 63) >> 6, tI, tJ)) return;
    const bool diag = (tI == tJ);

    const float* P = (mat ? T : S) + (size_t)n * CC * LL;
    unsigned short* Dout = (mat ? Dt : Ds) + (((size_t)t * NB + n) << 12);

    // staging: logical rows 0..127 = A rows 0..63 then B rows 64..127 (diag: A only)
    const int srow = w * 32 + (lane >> 1);
    const int half = lane & 1;                 // which 64 B half of the row's 128 B chunk
    const bool stager = diag ? (srow < 64) : true;
    const int ab = srow >> 6, rloc = srow & 63;
    const int gk = (ab ? tJ : tI) * 64 + rloc;
    const int row = s_idx[(gk < np) ? gk : 0];
    const char* rp = (const char*)P + (size_t)row * (LL * 4) + half * 64;

    float4 pre[4];
    float nsum = 0.0f;
    if (stager) {
        #pragma unroll
        for (int i = 0; i < 4; ++i) pre[i] = *(const float4*)(rp + i * 16);
    }

    const int m16 = lane & 15, quad = lane >> 4;
    const int bufB = diag ? 0 : 1;
    const int wrow = w * 16;

    floatx4 acc[4];
    #pragma unroll
    for (int c = 0; c < 4; ++c) { acc[c][0] = 0; acc[c][1] = 0; acc[c][2] = 0; acc[c][3] = 0; }

    for (int kk = 0; kk < 8; ++kk) {
        const int pb = kk & 1;
        if (stager) {
            // safe: chunk kk-2's reads of buf pb drained at barrier kk-1 (lgkmcnt)
            #pragma unroll
            for (int i = 0; i < 4; ++i)
                nsum += pre[i].x * pre[i].x + pre[i].y * pre[i].y +
                        pre[i].z * pre[i].z + pre[i].w * pre[i].w;
            unsigned short* dst = &lds[ab][pb][rloc][half * 16];
            *(uint2*)(dst + 0)  = make_uint2(f2bf2(pre[0].x, pre[0].y), f2bf2(pre[0].z, pre[0].w));
            *(uint2*)(dst + 4)  = make_uint2(f2bf2(pre[1].x, pre[1].y), f2bf2(pre[1].z, pre[1].w));
            *(uint2*)(dst + 8)  = make_uint2(f2bf2(pre[2].x, pre[2].y), f2bf2(pre[2].z, pre[2].w));
            *(uint2*)(dst + 12) = make_uint2(f2bf2(pre[3].x, pre[3].y), f2bf2(pre[3].z, pre[3].w));
        }
        __syncthreads();   // single barrier per chunk
        if (stager && kk < 7) {                // prefetch next chunk during MFMA
            #pragma unroll
            for (int i = 0; i < 4; ++i)
                pre[i] = *(const float4*)(rp + (kk + 1) * 128 + i * 16);
        }
        const short8 a = *(const short8*)&lds[0][pb][wrow + m16][quad * 8];
        #pragma unroll
        for (int c = 0; c < 4; ++c) {
            const short8 b = *(const short8*)&lds[bufB][pb][c * 16 + m16][quad * 8];
            acc[c] = __builtin_amdgcn_mfma_f32_16x16x32_bf16(a, b, acc[c], 0, 0, 0);
        }
    }

    // ---- inline norms: 2 lanes share each staged row ----
    if (stager) {
        const float v = nsum + __shfl_xor(nsum, 1);
        if (half == 0) s_norm[ab][rloc] = v;
    }
    __syncthreads();

    // ---- distances; C/D layout: col=lane&15, row=quad*4+reg ----
    float l0 = 0.0f;
    #pragma unroll
    for (int c = 0; c < 4; ++c) {
        const int colL = c * 16 + m16;
        const int gj = tJ * 64 + colL;
        const float nB = s_norm[bufB][colL];
        #pragma unroll
        for (int r = 0; r < 4; ++r) {
            const int rowL = wrow + quad * 4 + r;
            const int gi = tI * 64 + rowL;
            const float d = sqrtf(fmaxf(s_norm[0][rowL] + nB - 2.0f * acc[c][r], 1e-12f));
            if (gi < np && gj < np && gi != gj) l0 += d;
            Dout[rowL * 64 + colL] = f2h(d);
        }
    }

    #pragma unroll
    for (int o = 32; o; o >>= 1) l0 += __shfl_down(l0, o);
    if (lane == 0) red[w] = l0;
    __syncthreads();
    if (tid == 0) {
        const float wgt = diag ? 1.0f : 2.0f;  // off-diag tiles mirror-counted
        (mat ? sumT : sumS)[t * NB + n] = wgt * (red[0] + red[1] + red[2] + red[3]);
    }
}

// ---------------- K2: streaming Huber over fp16 Ds/Dt ----------------
// bx = t*64 + n: same XCD as the dist blocks that wrote this tile.
// Recomputes np from targets (ballot popcount), sums the per-tile slot sums
// with one wave-reduce (<=36 valid slots), then streams the fp16 tiles.
__global__ __launch_bounds__(256) void huber_kernel(
    const int* __restrict__ targets,
    const float* __restrict__ sumS, const float* __restrict__ sumT,
    const unsigned short* __restrict__ Ds, const unsigned short* __restrict__ Dt,
    float* __restrict__ out)
{
    const int bx = blockIdx.x;
    const int n = bx & (NB - 1), t = bx >> 6;
    const int tid = threadIdx.x;
    const int w = tid >> 6, lane = tid & 63;

    __shared__ int s_cnt[8];
    __shared__ float red[4];

    const int* tg = targets + n * CC;
    const unsigned long long m0 = __ballot(tg[tid] != 0);
    const unsigned long long m1 = __ballot(tg[tid + 256] != 0);
    if (lane == 0) { s_cnt[w] = __popcll(m0); s_cnt[4 + w] = __popcll(m1); }
    __syncthreads();
    int np = 0;
    #pragma unroll
    for (int i = 0; i < 8; ++i) np += s_cnt[i];   // LDS broadcast, block-uniform

    if (np < 2) return;
    const int u = (np + 63) >> 6;
    int tI, tJ;
    if (!decode_tile(t, u, tI, tJ)) return;
    const int ntiles = (u * (u + 1)) >> 1;

    // batch sums from unique slots: one wave-reduce per wave (redundant, no barrier)
    float a = 0.0f, b = 0.0f;
    if (lane < ntiles) { a = sumS[lane * NB + n]; b = sumT[lane * NB + n]; }
    #pragma unroll
    for (int o = 32; o; o >>= 1) { a += __shfl_down(a, o); b += __shfl_down(b, o); }
    a = __shfl(a, 0); b = __shfl(b, 0);

    const float cnt = (float)np * (float)(np - 1);
    const float inv_ms = cnt / a;
    const float inv_mt = cnt / b;

    const size_t slot = ((size_t)t * NB + n) << 12;
    const uint4* ps = (const uint4*)(Ds + slot);   // 4096 halves = 512 uint4
    const uint4* pt = (const uint4*)(Dt + slot);

    float h = 0.0f;
    #pragma unroll
    for (int it = 0; it < 2; ++it) {
        const int g = it * 256 + tid;              // uint4 group; 8 entries each
        const uint4 va = ps[g];
        const uint4 vb = pt[g];
        const unsigned aw[4] = { va.x, va.y, va.z, va.w };
        const unsigned bw[4] = { vb.x, vb.y, vb.z, vb.w };
        const int e0 = g * 8;
        #pragma unroll
        for (int k = 0; k < 8; ++k) {
            const int e = e0 + k;
            const int gi = tI * 64 + (e >> 6);
            const int gj = tJ * 64 + (e & 63);
            if (gi < np && gj < np && gi != gj) {
                const unsigned wa = aw[k >> 1], wb = bw[k >> 1];
                const float ds = h2f((k & 1) ? (wa >> 16) : (wa & 0xffffu));
                const float dt = h2f((k & 1) ? (wb >> 16) : (wb & 0xffffu));
                const float diff = ds * inv_ms - dt * inv_mt;
                const float ad = fabsf(diff);
                h += (ad < 1.0f) ? 0.5f * diff * diff : ad - 0.5f;
            }
        }
    }

    #pragma unroll
    for (int o = 32; o; o >>= 1) h += __shfl_down(h, o);
    if (lane == 0) red[w] = h;
    __syncthreads();
    if (tid == 0) {
        const float wgt = (tI == tJ) ? 1.0f : 2.0f;
        atomicAdd(out, wgt * (red[0] + red[1] + red[2] + red[3]) / (float)np);
    }
}

extern "C" void kernel_launch(void* const* d_in, const int* in_sizes, int n_in,
                              void* d_out, int out_size, void* d_ws, size_t ws_size,
                              hipStream_t stream) {
    const float* S = (const float*)d_in[0];
    const float* T = (const float*)d_in[1];
    const int* targets = (const int*)d_in[2];
    float* out = (float*)d_out;

    char* p = (char*)d_ws;
    float* sumS = (float*)p;   p += (size_t)36 * NB * 4;   // per-(t,n) slots
    float* sumT = (float*)p;   p += (size_t)36 * NB * 4;
    p = (char*)(((size_t)p + 255) & ~(size_t)255);
    unsigned short* Ds = (unsigned short*)p;   p += (size_t)36 * NB * 4096 * 2;  // 18.9 MB
    unsigned short* Dt = (unsigned short*)p;                                      // 18.9 MB

    dist_kernel<<<72 * NB, 256, 0, stream>>>(S, T, targets, sumS, sumT, Ds, Dt, out);
    huber_kernel<<<36 * NB, 256, 0, stream>>>(targets, sumS, sumT, Ds, Dt, out);
}